// Round 11
// baseline (323.932 us; speedup 1.0000x reference)
//
#include <hip/hip_runtime.h>

// ---------- types ----------
typedef __bf16 bf16x8 __attribute__((ext_vector_type(8)));
typedef float  f32x4  __attribute__((ext_vector_type(4)));

__device__ __forceinline__ unsigned short f2bf(float f) {
  unsigned int u = __builtin_bit_cast(unsigned int, f);
  u = (u + 0x7FFFu + ((u >> 16) & 1u)) >> 16;   // RNE
  return (unsigned short)u;
}
__device__ __forceinline__ float bf2f(unsigned short h) {
  return __builtin_bit_cast(float, (unsigned int)h << 16);
}

// async global->LDS, 16B per lane; LDS base must be wave-uniform
__device__ __forceinline__ void gload_lds16(const void* g, void* l) {
  __builtin_amdgcn_global_load_lds(
      (__attribute__((address_space(1))) void*)(unsigned long long)g,
      (__attribute__((address_space(3))) void*)(unsigned int)(unsigned long long)l,
      16, 0, 0);
}

// ============================================================================
// gemm_body: C = A[M,K] * Bt[N,K]^T.  128x128 tile, BK=32, 256 thr (4 waves).
// 2-deep pipeline, counted vmcnt (proven R4/R6/R9-correct).
// SWZ: bijective XCD block swizzle.  REV: reverse row order (longest causal-K
// blocks dispatch first -> no straggler tail).  Each caller is a distinctly
// named __global__ so rocprof attributes time per stage.
// ============================================================================
#define BM 128
#define BN 128
#define BK 32

template<int OUT_MODE, bool CAUSAL_TRI, bool CAUSAL_K, bool SWZ, bool REV>
__device__ __forceinline__ void gemm_body(
    const unsigned short* __restrict__ A, const unsigned short* __restrict__ Bt,
    void* __restrict__ Cv, const float* __restrict__ bias,
    int K, int lda, int ldb, int ldc,
    long long sA, long long sBt, long long sC)
{
  int bx = blockIdx.x, by = blockIdx.y;
  if (SWZ) {
    const int nwg = gridDim.x * gridDim.y;
    const int lin = blockIdx.y * gridDim.x + blockIdx.x;
    const int cpx = nwg >> 3;             // all grids have nwg % 8 == 0
    const int swz = (lin & 7) * cpx + (lin >> 3);
    bx = swz % gridDim.x;
    by = swz / gridDim.x;
  }
  if (REV) by = gridDim.y - 1 - by;       // longest-K blocks first
  const int m0 = by * BM;
  const int n0 = bx * BN;
  if (CAUSAL_TRI && n0 > m0) return;      // block-uniform early exit
  const int zb = blockIdx.z;
  A  += (long long)zb * sA;
  Bt += (long long)zb * sBt;

  __shared__ unsigned short As[2][BM * BK];   // 2 x 8 KB
  __shared__ unsigned short Bs[2][BN * BK];   // 2 x 8 KB

  const int tid  = threadIdx.x;
  const int wave = tid >> 6;
  const int lane = tid & 63;
  const int wr   = wave >> 1;
  const int wc   = wave & 1;
  const int ln15 = lane & 15;
  const int kq   = lane >> 4;

  f32x4 acc[4][4];
  #pragma unroll
  for (int i = 0; i < 4; ++i)
    #pragma unroll
    for (int j = 0; j < 4; ++j) {
      f32x4 z = {0.f, 0.f, 0.f, 0.f};
      acc[i][j] = z;
    }

  int Keff = K;
  if (CAUSAL_K) { int lim = m0 + BM; Keff = (K < lim) ? K : lim; }
  const int kTiles = Keff / BK;

  const int ar0 = tid >> 2;            // staging row
  const int ac0 = (tid & 3) << 3;      // staging col (8 elems = 16B)

  const unsigned short* A0 = A  + (size_t)(m0 + ar0)      * lda + ac0;
  const unsigned short* A1 = A  + (size_t)(m0 + 64 + ar0) * lda + ac0;
  const unsigned short* B0 = Bt + (size_t)(n0 + ar0)      * ldb + ac0;
  const unsigned short* B1 = Bt + (size_t)(n0 + 64 + ar0) * ldb + ac0;

  auto stage = [&](int buf, int kt) {
    const int k0 = kt * BK;
    gload_lds16(A0 + k0, &As[buf][wave * 512]);
    gload_lds16(A1 + k0, &As[buf][2048 + wave * 512]);
    gload_lds16(B0 + k0, &Bs[buf][wave * 512]);
    gload_lds16(B1 + k0, &Bs[buf][2048 + wave * 512]);
  };

  stage(0, 0);
  if (kTiles > 1) stage(1, 1);

  for (int kt = 0; kt < kTiles; ++kt) {
    const int cur = kt & 1;
    if (kt < kTiles - 1) asm volatile("s_waitcnt vmcnt(4)" ::: "memory");
    else                 asm volatile("s_waitcnt vmcnt(0)" ::: "memory");
    __builtin_amdgcn_sched_barrier(0);
    __builtin_amdgcn_s_barrier();
    __builtin_amdgcn_sched_barrier(0);

    bf16x8 af[4], bfr[4];
    #pragma unroll
    for (int i = 0; i < 4; ++i) {
      af[i]  = *reinterpret_cast<const bf16x8*>(&As[cur][(wr * 64 + i * 16 + ln15) * BK + kq * 8]);
      bfr[i] = *reinterpret_cast<const bf16x8*>(&Bs[cur][(wc * 64 + i * 16 + ln15) * BK + kq * 8]);
    }
    __builtin_amdgcn_sched_barrier(0);
    asm volatile("s_waitcnt lgkmcnt(0)" ::: "memory");
    __builtin_amdgcn_sched_barrier(0);
    __builtin_amdgcn_s_barrier();
    __builtin_amdgcn_sched_barrier(0);

    if (kt + 2 < kTiles) stage(cur, kt + 2);

    #pragma unroll
    for (int i = 0; i < 4; ++i)
      #pragma unroll
      for (int j = 0; j < 4; ++j)
        acc[i][j] = __builtin_amdgcn_mfma_f32_16x16x32_bf16(af[i], bfr[j], acc[i][j], 0, 0, 0);
  }

  // epilogue: C/D layout col = lane&15, row = (lane>>4)*4 + reg
  const int crow0 = m0 + wr * 64;
  const int ccol0 = n0 + wc * 64;
  float bvals[4] = {0.f, 0.f, 0.f, 0.f};
  if (OUT_MODE == 2) {
    #pragma unroll
    for (int j = 0; j < 4; ++j) bvals[j] = bias[ccol0 + j * 16 + ln15];
  }
  #pragma unroll
  for (int i = 0; i < 4; ++i) {
    const int r0 = crow0 + i * 16 + kq * 4;
    #pragma unroll
    for (int j = 0; j < 4; ++j) {
      const int c = ccol0 + j * 16 + ln15;
      #pragma unroll
      for (int rr = 0; rr < 4; ++rr) {
        const float vvv = acc[i][j][rr] + bvals[j];
        if (OUT_MODE == 1) {
          unsigned short* C = (unsigned short*)Cv + (long long)zb * sC;
          C[(size_t)(r0 + rr) * ldc + c] = f2bf(vvv);
        } else {
          float* C = (float*)Cv + (long long)zb * sC;
          C[(size_t)(r0 + rr) * ldc + c] = vvv;
        }
      }
    }
  }
}

// distinctly-named stage kernels (rocprof attribution)
__global__ __launch_bounds__(256) void qkv_gemm(
    const unsigned short* __restrict__ A, const unsigned short* __restrict__ Bt,
    void* __restrict__ Cv, int K, int lda, int ldb, int ldc) {
  gemm_body<1, false, false, true, false>(A, Bt, Cv, nullptr, K, lda, ldb, ldc, 0, 0, 0);
}
__global__ __launch_bounds__(256) void scores_gemm(
    const unsigned short* __restrict__ A, const unsigned short* __restrict__ Bt,
    void* __restrict__ Cv, int K, int lda, int ldb, int ldc,
    long long sA, long long sBt, long long sC) {
  gemm_body<0, true, false, true, false>(A, Bt, Cv, nullptr, K, lda, ldb, ldc, sA, sBt, sC);
}
__global__ __launch_bounds__(256) void pv_gemm(
    const unsigned short* __restrict__ A, const unsigned short* __restrict__ Bt,
    void* __restrict__ Cv, int K, int lda, int ldb, int ldc,
    long long sA, long long sBt, long long sC) {
  gemm_body<1, false, true, false, true>(A, Bt, Cv, nullptr, K, lda, ldb, ldc, sA, sBt, sC);
}
__global__ __launch_bounds__(256) void fc_gemm(
    const unsigned short* __restrict__ A, const unsigned short* __restrict__ Bt,
    void* __restrict__ Cv, const float* __restrict__ bias, int K, int lda, int ldb, int ldc) {
  gemm_body<2, false, false, true, false>(A, Bt, Cv, bias, K, lda, ldb, ldc, 0, 0, 0);
}

// ---------- helpers ----------
__global__ __launch_bounds__(256) void cast_f32_bf16(
    const float* __restrict__ in, unsigned short* __restrict__ out, long long n) {
  long long i = ((long long)blockIdx.x * 256 + threadIdx.x) * 4;
  if (i + 4 <= n) {
    const float4 v = *reinterpret_cast<const float4*>(in + i);
    ushort4 o;
    o.x = f2bf(v.x); o.y = f2bf(v.y); o.z = f2bf(v.z); o.w = f2bf(v.w);
    *reinterpret_cast<ushort4*>(out + i) = o;
  } else {
    for (; i < n; ++i) out[i] = f2bf(in[i]);
  }
}

// WT[o][i] = bf16(W[i][o]); 32x32 tiles via LDS; z selects one of 4 weights
__global__ void transcast_w4(
    const float* __restrict__ W0, const float* __restrict__ W1,
    const float* __restrict__ W2, const float* __restrict__ W3,
    unsigned short* __restrict__ T0, unsigned short* __restrict__ T1,
    unsigned short* __restrict__ T2, unsigned short* __restrict__ T3,
    int rows, int cols) {
  const int z = blockIdx.z;
  const float* W = (z == 0) ? W0 : (z == 1) ? W1 : (z == 2) ? W2 : W3;
  unsigned short* WT = (z == 0) ? T0 : (z == 1) ? T1 : (z == 2) ? T2 : T3;
  __shared__ float tile[32][33];
  const int c0 = blockIdx.x * 32, r0 = blockIdx.y * 32;
  const int tx = threadIdx.x, ty = threadIdx.y;
  #pragma unroll
  for (int r = ty; r < 32; r += 8)
    tile[r][tx] = W[(size_t)(r0 + r) * cols + (c0 + tx)];
  __syncthreads();
  #pragma unroll
  for (int r = ty; r < 32; r += 8)
    WT[(size_t)(c0 + r) * rows + (r0 + tx)] = f2bf(tile[tx][r]);
}

// per-batch bf16 transpose with input ld: VT[b][d][n] = V[b][n][d]
__global__ void trans_bf16(const unsigned short* __restrict__ V, unsigned short* __restrict__ VT,
                           int rows, int cols, int ld_in, long long sIn, long long sOut) {
  const size_t bi = (size_t)blockIdx.z * sIn;
  const size_t bo = (size_t)blockIdx.z * sOut;
  __shared__ unsigned short tile[32][33];
  const int c0 = blockIdx.x * 32, r0 = blockIdx.y * 32;
  const int tx = threadIdx.x, ty = threadIdx.y;
  #pragma unroll
  for (int r = ty; r < 32; r += 8)
    tile[r][tx] = V[bi + (size_t)(r0 + r) * ld_in + (c0 + tx)];
  __syncthreads();
  #pragma unroll
  for (int r = ty; r < 32; r += 8)
    VT[bo + (size_t)(c0 + r) * rows + (r0 + tx)] = tile[tx][r];
}

// causal row softmax, single-pass: row (N=2048 fp32) in registers (8/thread)
__global__ __launch_bounds__(256) void softmax_causal(
    const float* __restrict__ S, unsigned short* __restrict__ att, int N, float scale) {
  const int row = blockIdx.x;
  const int b = row / N;
  const int r = row - b * N;
  const float* s = S + (size_t)b * N * N + (size_t)r * N;
  unsigned short* a = att + (size_t)b * N * N + (size_t)r * N;
  const int L = r + 1;
  const int Lpad = (L + 127) & ~127;   // PV (128-tile) reads k < roundup(row+1,128)
  const int tid = threadIdx.x;
  const int j0 = tid * 8;
  const bool active = j0 < Lpad;

  float v[8];
  if (active) {
    const float4 p0 = *reinterpret_cast<const float4*>(s + j0);
    const float4 p1 = *reinterpret_cast<const float4*>(s + j0 + 4);
    v[0] = p0.x; v[1] = p0.y; v[2] = p0.z; v[3] = p0.w;
    v[4] = p1.x; v[5] = p1.y; v[6] = p1.z; v[7] = p1.w;
  }

  __shared__ float redm[4], reds[4];

  float mx = -3.0e38f;
  if (active) {
    #pragma unroll
    for (int k = 0; k < 8; ++k) mx = fmaxf(mx, (j0 + k < L) ? v[k] : -3.0e38f);
  }
  #pragma unroll
  for (int o = 32; o > 0; o >>= 1) mx = fmaxf(mx, __shfl_xor(mx, o, 64));
  if ((tid & 63) == 0) redm[tid >> 6] = mx;
  __syncthreads();
  mx = fmaxf(fmaxf(redm[0], redm[1]), fmaxf(redm[2], redm[3]));

  float e[8];
  float sum = 0.f;
  if (active) {
    #pragma unroll
    for (int k = 0; k < 8; ++k) {
      e[k] = (j0 + k < L) ? __expf((v[k] - mx) * scale) : 0.f;
      sum += e[k];
    }
  }
  #pragma unroll
  for (int o = 32; o > 0; o >>= 1) sum += __shfl_xor(sum, o, 64);
  if ((tid & 63) == 0) reds[tid >> 6] = sum;
  __syncthreads();
  sum = reds[0] + reds[1] + reds[2] + reds[3];
  const float inv = 1.f / sum;

  if (active) {
    uint4 w;
    unsigned int t0 = f2bf(e[0] * inv), t1 = f2bf(e[1] * inv);
    unsigned int t2 = f2bf(e[2] * inv), t3 = f2bf(e[3] * inv);
    unsigned int t4 = f2bf(e[4] * inv), t5 = f2bf(e[5] * inv);
    unsigned int t6 = f2bf(e[6] * inv), t7 = f2bf(e[7] * inv);
    w.x = t0 | (t1 << 16); w.y = t2 | (t3 << 16);
    w.z = t4 | (t5 << 16); w.w = t6 | (t7 << 16);
    *reinterpret_cast<uint4*>(a + j0) = w;
  }
}

// h = LN(attout + v) * gamma + beta  (D=1024, 256 thr x 4 contiguous)
__global__ __launch_bounds__(256) void add_layernorm(
    const unsigned short* __restrict__ ao, const unsigned short* __restrict__ qkv,
    int ldv, int voff,
    const float* __restrict__ gamma, const float* __restrict__ beta,
    unsigned short* __restrict__ h) {
  const size_t base  = (size_t)blockIdx.x * 1024;
  const size_t vbase = (size_t)blockIdx.x * ldv + voff;
  const int tid = threadIdx.x;
  const int j = tid * 4;

  const ushort4 a4 = *reinterpret_cast<const ushort4*>(ao + base + j);
  const ushort4 v4 = *reinterpret_cast<const ushort4*>(qkv + vbase + j);
  float xv[4];
  xv[0] = bf2f(a4.x) + bf2f(v4.x);
  xv[1] = bf2f(a4.y) + bf2f(v4.y);
  xv[2] = bf2f(a4.z) + bf2f(v4.z);
  xv[3] = bf2f(a4.w) + bf2f(v4.w);
  float sum = xv[0] + xv[1] + xv[2] + xv[3];
  float sq  = xv[0]*xv[0] + xv[1]*xv[1] + xv[2]*xv[2] + xv[3]*xv[3];

  #pragma unroll
  for (int o = 32; o > 0; o >>= 1) { sum += __shfl_xor(sum, o, 64); sq += __shfl_xor(sq, o, 64); }
  __shared__ float rs_[4], rq_[4];
  if ((tid & 63) == 0) { rs_[tid >> 6] = sum; rq_[tid >> 6] = sq; }
  __syncthreads();
  sum = rs_[0] + rs_[1] + rs_[2] + rs_[3];
  sq  = rq_[0] + rq_[1] + rq_[2] + rq_[3];
  const float mu   = sum * (1.f / 1024.f);
  const float var  = sq * (1.f / 1024.f) - mu * mu;
  const float rstd = rsqrtf(var + 1e-5f);

  const float4 g4 = *reinterpret_cast<const float4*>(gamma + j);
  const float4 b4 = *reinterpret_cast<const float4*>(beta + j);
  ushort4 o4;
  o4.x = f2bf((xv[0] - mu) * rstd * g4.x + b4.x);
  o4.y = f2bf((xv[1] - mu) * rstd * g4.y + b4.y);
  o4.z = f2bf((xv[2] - mu) * rstd * g4.z + b4.z);
  o4.w = f2bf((xv[3] - mu) * rstd * g4.w + b4.w);
  *reinterpret_cast<ushort4*>(h + base + j) = o4;
}

// ---------- launch ----------
extern "C" void kernel_launch(void* const* d_in, const int* in_sizes, int n_in,
                              void* d_out, int out_size, void* d_ws, size_t ws_size,
                              hipStream_t stream) {
  const float* x     = (const float*)d_in[0];
  const float* Wq    = (const float*)d_in[1];
  const float* Wk    = (const float*)d_in[2];
  const float* Wv    = (const float*)d_in[3];
  const float* Wfc   = (const float*)d_in[4];
  const float* bfc   = (const float*)d_in[5];
  const float* gamma = (const float*)d_in[6];
  const float* beta  = (const float*)d_in[7];
  float* out = (float*)d_out;

  const int Bn = 4, Nn = 2048, Dn = 1024;
  const int M = Bn * Nn;                       // 8192
  const int D3 = 3 * Dn;                       // 3072

  char* ws = (char*)d_ws;
  size_t off = 0;
  auto alloc = [&](size_t bytes) { void* p = ws + off; off += (bytes + 255) & ~255ULL; return p; };
  unsigned short* xb    = (unsigned short*)alloc((size_t)M * Dn * 2);        // 16 MB
  unsigned short* WqkvT = (unsigned short*)alloc((size_t)D3 * Dn * 2);       // 6 MB
  unsigned short* WfcT  = (unsigned short*)alloc((size_t)Dn * Dn * 2);       // 2 MB
  unsigned short* QKV   = (unsigned short*)alloc((size_t)M * D3 * 2);        // 48 MB
  unsigned short* VTb   = (unsigned short*)alloc((size_t)M * Dn * 2);        // 16 MB
  float*          S     = (float*)alloc((size_t)Bn * Nn * Nn * 4);           // 64 MB
  unsigned short* att   = (unsigned short*)alloc((size_t)Bn * Nn * Nn * 2);  // 32 MB
  // S is dead after softmax -> reuse for ao and h
  unsigned short* ao = (unsigned short*)S;
  unsigned short* h  = (unsigned short*)S + (size_t)M * Dn;

  unsigned short* Qp = QKV;               // ld D3
  unsigned short* Kp = QKV + Dn;          // ld D3
  unsigned short* Vp = QKV + 2 * Dn;      // ld D3

  const dim3 blk(256);

  // 1. casts
  cast_f32_bf16<<<dim3(((long long)M * Dn) / 1024), blk, 0, stream>>>(x, xb, (long long)M * Dn);
  const dim3 tb(32, 8, 1);
  transcast_w4<<<dim3(Dn / 32, Dn / 32, 4), tb, 0, stream>>>(
      Wq, Wk, Wv, Wfc,
      WqkvT, WqkvT + (size_t)Dn * Dn, WqkvT + (size_t)2 * Dn * Dn, WfcT, Dn, Dn);

  // 2. fused QKV projection: [8192,1024] x [3072,1024]^T -> [8192,3072] bf16
  qkv_gemm<<<dim3(D3 / BN, M / BM, 1), blk, 0, stream>>>(
      xb, WqkvT, QKV, Dn, Dn, Dn, D3);

  // 3. V^T for PV
  trans_bf16<<<dim3(Dn / 32, Nn / 32, Bn), tb, 0, stream>>>(
      Vp, VTb, Nn, Dn, D3, (long long)Nn * D3, (long long)Dn * Nn);

  // 4. scores = Q K^T (lower-triangle tiles only), fp32
  scores_gemm<<<dim3(Nn / BN, Nn / BM, Bn), blk, 0, stream>>>(
      Qp, Kp, S, Dn, D3, D3, Nn,
      (long long)Nn * D3, (long long)Nn * D3, (long long)Nn * Nn);

  // 5. causal softmax -> bf16 att (zero-padded to 128 boundary)
  softmax_causal<<<dim3(Bn * Nn), blk, 0, stream>>>(S, att, Nn, 0.03125f);

  // 6. attout = att @ V  (K limited to diagonal block; longest rows first)
  pv_gemm<<<dim3(Dn / BN, Nn / BM, Bn), blk, 0, stream>>>(
      att, VTb, ao, Nn, Nn, Nn, Dn,
      (long long)Nn * Nn, (long long)Dn * Nn, (long long)Nn * Dn);

  // 7. h = LN(attout + v)
  add_layernorm<<<dim3(Bn * Nn), blk, 0, stream>>>(ao, QKV, D3, 2 * Dn, gamma, beta, h);

  // 8. out = h @ Wfc + bfc, fp32
  fc_gemm<<<dim3(Dn / BN, M / BM, 1), blk, 0, stream>>>(
      h, WfcT, out, bfc, Dn, Dn, Dn, Dn);
}

// Round 13
// 312.003 us; speedup vs baseline: 1.0382x; 1.0382x over previous
//
#include <hip/hip_runtime.h>

// ---------- types ----------
typedef __bf16 bf16x8 __attribute__((ext_vector_type(8)));
typedef float  f32x4  __attribute__((ext_vector_type(4)));

__device__ __forceinline__ unsigned short f2bf(float f) {
  unsigned int u = __builtin_bit_cast(unsigned int, f);
  u = (u + 0x7FFFu + ((u >> 16) & 1u)) >> 16;   // RNE
  return (unsigned short)u;
}
__device__ __forceinline__ float bf2f(unsigned short h) {
  return __builtin_bit_cast(float, (unsigned int)h << 16);
}

// async global->LDS, 16B per lane; LDS base must be wave-uniform
__device__ __forceinline__ void gload_lds16(const void* g, void* l) {
  __builtin_amdgcn_global_load_lds(
      (__attribute__((address_space(1))) void*)(unsigned long long)g,
      (__attribute__((address_space(3))) void*)(unsigned int)(unsigned long long)l,
      16, 0, 0);
}

// ============================================================================
// gemm_body: C = A[M,K] * Bt[N,K]^T.  128x128 tile, BK=32, 256 thr (4 waves).
// 2-deep pipeline, counted vmcnt (proven R4..R11-correct).  Callers compute
// (bx, by, zb) block coords (swizzle / packed-triangle / reversed).
// ============================================================================
#define BM 128
#define BN 128
#define BK 32

template<int OUT_MODE, bool CAUSAL_K>
__device__ __forceinline__ void gemm_body(
    int bx, int by, int zb,
    const unsigned short* __restrict__ A, const unsigned short* __restrict__ Bt,
    void* __restrict__ Cv, const float* __restrict__ bias,
    int K, int lda, int ldb, int ldc,
    long long sA, long long sBt, long long sC)
{
  const int m0 = by * BM;
  const int n0 = bx * BN;
  A  += (long long)zb * sA;
  Bt += (long long)zb * sBt;

  __shared__ unsigned short As[2][BM * BK];   // 2 x 8 KB
  __shared__ unsigned short Bs[2][BN * BK];   // 2 x 8 KB

  const int tid  = threadIdx.x;
  const int wave = tid >> 6;
  const int lane = tid & 63;
  const int wr   = wave >> 1;
  const int wc   = wave & 1;
  const int ln15 = lane & 15;
  const int kq   = lane >> 4;

  f32x4 acc[4][4];
  #pragma unroll
  for (int i = 0; i < 4; ++i)
    #pragma unroll
    for (int j = 0; j < 4; ++j) {
      f32x4 z = {0.f, 0.f, 0.f, 0.f};
      acc[i][j] = z;
    }

  int Keff = K;
  if (CAUSAL_K) { int lim = m0 + BM; Keff = (K < lim) ? K : lim; }
  const int kTiles = Keff / BK;

  const int ar0 = tid >> 2;            // staging row
  const int ac0 = (tid & 3) << 3;      // staging col (8 elems = 16B)

  const unsigned short* A0 = A  + (size_t)(m0 + ar0)      * lda + ac0;
  const unsigned short* A1 = A  + (size_t)(m0 + 64 + ar0) * lda + ac0;
  const unsigned short* B0 = Bt + (size_t)(n0 + ar0)      * ldb + ac0;
  const unsigned short* B1 = Bt + (size_t)(n0 + 64 + ar0) * ldb + ac0;

  auto stage = [&](int buf, int kt) {
    const int k0 = kt * BK;
    gload_lds16(A0 + k0, &As[buf][wave * 512]);
    gload_lds16(A1 + k0, &As[buf][2048 + wave * 512]);
    gload_lds16(B0 + k0, &Bs[buf][wave * 512]);
    gload_lds16(B1 + k0, &Bs[buf][2048 + wave * 512]);
  };

  stage(0, 0);
  if (kTiles > 1) stage(1, 1);

  for (int kt = 0; kt < kTiles; ++kt) {
    const int cur = kt & 1;
    if (kt < kTiles - 1) asm volatile("s_waitcnt vmcnt(4)" ::: "memory");
    else                 asm volatile("s_waitcnt vmcnt(0)" ::: "memory");
    __builtin_amdgcn_sched_barrier(0);
    __builtin_amdgcn_s_barrier();
    __builtin_amdgcn_sched_barrier(0);

    bf16x8 af[4], bfr[4];
    #pragma unroll
    for (int i = 0; i < 4; ++i) {
      af[i]  = *reinterpret_cast<const bf16x8*>(&As[cur][(wr * 64 + i * 16 + ln15) * BK + kq * 8]);
      bfr[i] = *reinterpret_cast<const bf16x8*>(&Bs[cur][(wc * 64 + i * 16 + ln15) * BK + kq * 8]);
    }
    __builtin_amdgcn_sched_barrier(0);
    asm volatile("s_waitcnt lgkmcnt(0)" ::: "memory");
    __builtin_amdgcn_sched_barrier(0);
    __builtin_amdgcn_s_barrier();
    __builtin_amdgcn_sched_barrier(0);

    if (kt + 2 < kTiles) stage(cur, kt + 2);

    #pragma unroll
    for (int i = 0; i < 4; ++i)
      #pragma unroll
      for (int j = 0; j < 4; ++j)
        acc[i][j] = __builtin_amdgcn_mfma_f32_16x16x32_bf16(af[i], bfr[j], acc[i][j], 0, 0, 0);
  }

  // epilogue: C/D layout col = lane&15, row = (lane>>4)*4 + reg
  const int crow0 = m0 + wr * 64;
  const int ccol0 = n0 + wc * 64;
  float bvals[4] = {0.f, 0.f, 0.f, 0.f};
  if (OUT_MODE == 2) {
    #pragma unroll
    for (int j = 0; j < 4; ++j) bvals[j] = bias[ccol0 + j * 16 + ln15];
  }
  #pragma unroll
  for (int i = 0; i < 4; ++i) {
    const int r0 = crow0 + i * 16 + kq * 4;
    #pragma unroll
    for (int j = 0; j < 4; ++j) {
      const int c = ccol0 + j * 16 + ln15;
      #pragma unroll
      for (int rr = 0; rr < 4; ++rr) {
        const float vvv = acc[i][j][rr] + bvals[j];
        if (OUT_MODE == 1) {
          unsigned short* C = (unsigned short*)Cv + (long long)zb * sC;
          C[(size_t)(r0 + rr) * ldc + c] = f2bf(vvv);
        } else {
          float* C = (float*)Cv + (long long)zb * sC;
          C[(size_t)(r0 + rr) * ldc + c] = vvv;
        }
      }
    }
  }
}

// bijective XCD swizzle for 2D grids with nwg % 8 == 0
__device__ __forceinline__ void swz8(int& bx, int& by) {
  const int nwg = gridDim.x * gridDim.y;
  const int lin = blockIdx.y * gridDim.x + blockIdx.x;
  const int cpx = nwg >> 3;
  const int swz = (lin & 7) * cpx + (lin >> 3);
  bx = swz % gridDim.x;
  by = swz / gridDim.x;
}

// ---- stage kernels (distinct names for rocprof attribution) ----
__global__ __launch_bounds__(256) void qkv_gemm(
    const unsigned short* __restrict__ A, const unsigned short* __restrict__ Bt,
    void* __restrict__ Cv, int K, int lda, int ldb, int ldc) {
  int bx, by; swz8(bx, by);
  gemm_body<1, false>(bx, by, 0, A, Bt, Cv, nullptr, K, lda, ldb, ldc, 0, 0, 0);
}

// packed lower-triangle grid: blockIdx.x in [0, T*(T+1)/2) -> (row, col)
__global__ __launch_bounds__(256) void scores_gemm(
    const unsigned short* __restrict__ A, const unsigned short* __restrict__ Bt,
    void* __restrict__ Cv, int K, int lda, int ldb, int ldc,
    long long sA, long long sBt, long long sC) {
  const int idx = blockIdx.x;
  int r = (int)((sqrtf(8.f * (float)idx + 1.f) - 1.f) * 0.5f);
  while ((r + 1) * (r + 2) / 2 <= idx) ++r;
  while (r * (r + 1) / 2 > idx) --r;
  const int c = idx - r * (r + 1) / 2;   // c <= r: lower triangle
  gemm_body<0, false>(c, r, blockIdx.z, A, Bt, Cv, nullptr, K, lda, ldb, ldc, sA, sBt, sC);
}

__global__ __launch_bounds__(256) void pv_gemm(
    const unsigned short* __restrict__ A, const unsigned short* __restrict__ Bt,
    void* __restrict__ Cv, int K, int lda, int ldb, int ldc,
    long long sA, long long sBt, long long sC) {
  const int by = gridDim.y - 1 - blockIdx.y;   // longest causal-K blocks first
  gemm_body<1, true>(blockIdx.x, by, blockIdx.z, A, Bt, Cv, nullptr, K, lda, ldb, ldc, sA, sBt, sC);
}

__global__ __launch_bounds__(256) void fc_gemm(
    const unsigned short* __restrict__ A, const unsigned short* __restrict__ Bt,
    void* __restrict__ Cv, const float* __restrict__ bias, int K, int lda, int ldb, int ldc) {
  int bx, by; swz8(bx, by);
  gemm_body<2, false>(bx, by, 0, A, Bt, Cv, bias, K, lda, ldb, ldc, 0, 0, 0);
}

// ---------- helpers ----------
__global__ __launch_bounds__(256) void cast_f32_bf16(
    const float* __restrict__ in, unsigned short* __restrict__ out, long long n) {
  long long i = ((long long)blockIdx.x * 256 + threadIdx.x) * 4;
  if (i + 4 <= n) {
    const float4 v = *reinterpret_cast<const float4*>(in + i);
    ushort4 o;
    o.x = f2bf(v.x); o.y = f2bf(v.y); o.z = f2bf(v.z); o.w = f2bf(v.w);
    *reinterpret_cast<ushort4*>(out + i) = o;
  } else {
    for (; i < n; ++i) out[i] = f2bf(in[i]);
  }
}

// WT[o][i] = bf16(W[i][o]); 32x32 tiles via LDS; z selects one of 4 weights
__global__ void transcast_w4(
    const float* __restrict__ W0, const float* __restrict__ W1,
    const float* __restrict__ W2, const float* __restrict__ W3,
    unsigned short* __restrict__ T0, unsigned short* __restrict__ T1,
    unsigned short* __restrict__ T2, unsigned short* __restrict__ T3,
    int rows, int cols) {
  const int z = blockIdx.z;
  const float* W = (z == 0) ? W0 : (z == 1) ? W1 : (z == 2) ? W2 : W3;
  unsigned short* WT = (z == 0) ? T0 : (z == 1) ? T1 : (z == 2) ? T2 : T3;
  __shared__ float tile[32][33];
  const int c0 = blockIdx.x * 32, r0 = blockIdx.y * 32;
  const int tx = threadIdx.x, ty = threadIdx.y;
  #pragma unroll
  for (int r = ty; r < 32; r += 8)
    tile[r][tx] = W[(size_t)(r0 + r) * cols + (c0 + tx)];
  __syncthreads();
  #pragma unroll
  for (int r = ty; r < 32; r += 8)
    WT[(size_t)(c0 + r) * rows + (r0 + tx)] = f2bf(tile[tx][r]);
}

// vectorized per-batch bf16 transpose: 64x64 tiles, 16B loads/stores via LDS
// VT[b][d][n] = V[b][n][d]
__global__ __launch_bounds__(256) void trans_bf16(
    const unsigned short* __restrict__ V, unsigned short* __restrict__ VT,
    int rows, int cols, int ld_in, long long sIn, long long sOut) {
  const size_t bi = (size_t)blockIdx.z * sIn;
  const size_t bo = (size_t)blockIdx.z * sOut;
  __shared__ unsigned short t[64][72];   // +8 pad: transposed reads ~2-way (free)
  const int c0 = blockIdx.x * 64, r0 = blockIdx.y * 64;
  const int tid = threadIdx.x;
  const int cg  = tid & 7;               // 16B column group
  const int rr  = tid >> 3;              // 0..31

  #pragma unroll
  for (int p = 0; p < 2; ++p) {
    const int row = rr + p * 32;
    *reinterpret_cast<uint4*>(&t[row][cg * 8]) =
        *reinterpret_cast<const uint4*>(&V[bi + (size_t)(r0 + row) * ld_in + c0 + cg * 8]);
  }
  __syncthreads();
  #pragma unroll
  for (int p = 0; p < 2; ++p) {
    const int d = rr + p * 32;           // output row (= input col)
    unsigned short tmp[8];
    #pragma unroll
    for (int j = 0; j < 8; ++j) tmp[j] = t[cg * 8 + j][d];
    *reinterpret_cast<uint4*>(&VT[bo + (size_t)(c0 + d) * rows + r0 + cg * 8]) =
        *reinterpret_cast<const uint4*>(tmp);
  }
}

// causal row softmax, single-pass, IN-PLACE: row (N fp32) read to registers,
// att bf16 written into the first 2N bytes of the SAME row.  Reads complete
// before the reduction barriers; writes happen after -> no intra-block hazard.
__global__ __launch_bounds__(256) void softmax_causal(
    float* __restrict__ S, int N, float scale) {
  const int row = blockIdx.x;
  const int b = row / N;
  const int r = row - b * N;
  float* s = S + (size_t)b * N * N + (size_t)r * N;
  unsigned short* a = (unsigned short*)s;         // in-place bf16 row
  const int L = r + 1;
  const int Lpad = (L + 127) & ~127;   // PV reads k < roundup(row+1,128)
  const int tid = threadIdx.x;
  const int j0 = tid * 8;
  const bool active = j0 < Lpad;

  float v[8];
  if (active) {
    const uint4 u0 = *reinterpret_cast<const uint4*>(s + j0);
    const uint4 u1 = *reinterpret_cast<const uint4*>(s + j0 + 4);
    v[0] = __builtin_bit_cast(float, u0.x); v[1] = __builtin_bit_cast(float, u0.y);
    v[2] = __builtin_bit_cast(float, u0.z); v[3] = __builtin_bit_cast(float, u0.w);
    v[4] = __builtin_bit_cast(float, u1.x); v[5] = __builtin_bit_cast(float, u1.y);
    v[6] = __builtin_bit_cast(float, u1.z); v[7] = __builtin_bit_cast(float, u1.w);
  }

  __shared__ float redm[4], reds[4];

  float mx = -3.0e38f;
  if (active) {
    #pragma unroll
    for (int k = 0; k < 8; ++k) mx = fmaxf(mx, (j0 + k < L) ? v[k] : -3.0e38f);
  }
  #pragma unroll
  for (int o = 32; o > 0; o >>= 1) mx = fmaxf(mx, __shfl_xor(mx, o, 64));
  if ((tid & 63) == 0) redm[tid >> 6] = mx;
  __syncthreads();
  mx = fmaxf(fmaxf(redm[0], redm[1]), fmaxf(redm[2], redm[3]));

  float e[8];
  float sum = 0.f;
  if (active) {
    #pragma unroll
    for (int k = 0; k < 8; ++k) {
      e[k] = (j0 + k < L) ? __expf((v[k] - mx) * scale) : 0.f;
      sum += e[k];
    }
  }
  #pragma unroll
  for (int o = 32; o > 0; o >>= 1) sum += __shfl_xor(sum, o, 64);
  if ((tid & 63) == 0) reds[tid >> 6] = sum;
  __syncthreads();            // also orders all reads before the in-place writes
  sum = reds[0] + reds[1] + reds[2] + reds[3];
  const float inv = 1.f / sum;

  if (active) {
    uint4 w;
    unsigned int t0 = f2bf(e[0] * inv), t1 = f2bf(e[1] * inv);
    unsigned int t2 = f2bf(e[2] * inv), t3 = f2bf(e[3] * inv);
    unsigned int t4 = f2bf(e[4] * inv), t5 = f2bf(e[5] * inv);
    unsigned int t6 = f2bf(e[6] * inv), t7 = f2bf(e[7] * inv);
    w.x = t0 | (t1 << 16); w.y = t2 | (t3 << 16);
    w.z = t4 | (t5 << 16); w.w = t6 | (t7 << 16);
    *reinterpret_cast<uint4*>(a + j0) = w;   // bytes [2*j0, 2*j0+16) of own row
  }
}

// h = LN(attout + v) * gamma + beta  (D=1024, 256 thr x 4 contiguous)
__global__ __launch_bounds__(256) void add_layernorm(
    const unsigned short* __restrict__ ao, const unsigned short* __restrict__ qkv,
    int ldv, int voff,
    const float* __restrict__ gamma, const float* __restrict__ beta,
    unsigned short* __restrict__ h) {
  const size_t base  = (size_t)blockIdx.x * 1024;
  const size_t vbase = (size_t)blockIdx.x * ldv + voff;
  const int tid = threadIdx.x;
  const int j = tid * 4;

  const ushort4 a4 = *reinterpret_cast<const ushort4*>(ao + base + j);
  const ushort4 v4 = *reinterpret_cast<const ushort4*>(qkv + vbase + j);
  float xv[4];
  xv[0] = bf2f(a4.x) + bf2f(v4.x);
  xv[1] = bf2f(a4.y) + bf2f(v4.y);
  xv[2] = bf2f(a4.z) + bf2f(v4.z);
  xv[3] = bf2f(a4.w) + bf2f(v4.w);
  float sum = xv[0] + xv[1] + xv[2] + xv[3];
  float sq  = xv[0]*xv[0] + xv[1]*xv[1] + xv[2]*xv[2] + xv[3]*xv[3];

  #pragma unroll
  for (int o = 32; o > 0; o >>= 1) { sum += __shfl_xor(sum, o, 64); sq += __shfl_xor(sq, o, 64); }
  __shared__ float rs_[4], rq_[4];
  if ((tid & 63) == 0) { rs_[tid >> 6] = sum; rq_[tid >> 6] = sq; }
  __syncthreads();
  sum = rs_[0] + rs_[1] + rs_[2] + rs_[3];
  sq  = rq_[0] + rq_[1] + rq_[2] + rq_[3];
  const float mu   = sum * (1.f / 1024.f);
  const float var  = sq * (1.f / 1024.f) - mu * mu;
  const float rstd = rsqrtf(var + 1e-5f);

  const float4 g4 = *reinterpret_cast<const float4*>(gamma + j);
  const float4 b4 = *reinterpret_cast<const float4*>(beta + j);
  ushort4 o4;
  o4.x = f2bf((xv[0] - mu) * rstd * g4.x + b4.x);
  o4.y = f2bf((xv[1] - mu) * rstd * g4.y + b4.y);
  o4.z = f2bf((xv[2] - mu) * rstd * g4.z + b4.z);
  o4.w = f2bf((xv[3] - mu) * rstd * g4.w + b4.w);
  *reinterpret_cast<ushort4*>(h + base + j) = o4;
}

// ---------- launch ----------
extern "C" void kernel_launch(void* const* d_in, const int* in_sizes, int n_in,
                              void* d_out, int out_size, void* d_ws, size_t ws_size,
                              hipStream_t stream) {
  const float* x     = (const float*)d_in[0];
  const float* Wq    = (const float*)d_in[1];
  const float* Wk    = (const float*)d_in[2];
  const float* Wv    = (const float*)d_in[3];
  const float* Wfc   = (const float*)d_in[4];
  const float* bfc   = (const float*)d_in[5];
  const float* gamma = (const float*)d_in[6];
  const float* beta  = (const float*)d_in[7];
  float* out = (float*)d_out;

  const int Bn = 4, Nn = 2048, Dn = 1024;
  const int M = Bn * Nn;                       // 8192
  const int D3 = 3 * Dn;                       // 3072

  char* ws = (char*)d_ws;
  size_t off = 0;
  auto alloc = [&](size_t bytes) { void* p = ws + off; off += (bytes + 255) & ~255ULL; return p; };
  unsigned short* xb    = (unsigned short*)alloc((size_t)M * Dn * 2);        // 16 MB
  unsigned short* WqkvT = (unsigned short*)alloc((size_t)D3 * Dn * 2);       // 6 MB
  unsigned short* WfcT  = (unsigned short*)alloc((size_t)Dn * Dn * 2);       // 2 MB
  unsigned short* QKV   = (unsigned short*)alloc((size_t)M * D3 * 2);        // 48 MB
  unsigned short* VTb   = (unsigned short*)alloc((size_t)M * Dn * 2);        // 16 MB
  float*          S     = (float*)alloc((size_t)Bn * Nn * Nn * 4);           // 64 MB
  // total 152 MB.  att lives IN-PLACE inside S (first 2N bytes of each fp32 row).
  unsigned short* ao = xb;                     // xb dead after qkv_gemm
  unsigned short* h  = VTb;                    // VTb dead after pv_gemm

  unsigned short* Qp = QKV;               // ld D3
  unsigned short* Kp = QKV + Dn;          // ld D3
  unsigned short* Vp = QKV + 2 * Dn;      // ld D3

  const dim3 blk(256);

  // 1. casts
  cast_f32_bf16<<<dim3(((long long)M * Dn) / 1024), blk, 0, stream>>>(x, xb, (long long)M * Dn);
  const dim3 tb(32, 8, 1);
  transcast_w4<<<dim3(Dn / 32, Dn / 32, 4), tb, 0, stream>>>(
      Wq, Wk, Wv, Wfc,
      WqkvT, WqkvT + (size_t)Dn * Dn, WqkvT + (size_t)2 * Dn * Dn, WfcT, Dn, Dn);

  // 2. fused QKV projection: [8192,1024] x [3072,1024]^T -> [8192,3072] bf16
  qkv_gemm<<<dim3(D3 / BN, M / BM, 1), blk, 0, stream>>>(
      xb, WqkvT, QKV, Dn, Dn, Dn, D3);

  // 3. V^T for PV (vectorized 64x64 tiles)
  trans_bf16<<<dim3(Dn / 64, Nn / 64, Bn), blk, 0, stream>>>(
      Vp, VTb, Nn, Dn, D3, (long long)Nn * D3, (long long)Dn * Nn);

  // 4. scores = Q K^T, packed lower-triangle grid (136 tiles/batch), fp32
  scores_gemm<<<dim3((Nn / BM) * (Nn / BM + 1) / 2, 1, Bn), blk, 0, stream>>>(
      Qp, Kp, S, Dn, D3, D3, Nn,
      (long long)Nn * D3, (long long)Nn * D3, (long long)Nn * Nn);

  // 5. causal softmax -> bf16 att IN-PLACE in S (zero-padded to 128 boundary)
  softmax_causal<<<dim3(Bn * Nn), blk, 0, stream>>>(S, Nn, 0.03125f);

  // 6. attout = att @ V  (att strided inside S: row stride 2N ushorts)
  pv_gemm<<<dim3(Dn / BN, Nn / BM, Bn), blk, 0, stream>>>(
      (unsigned short*)S, VTb, ao, Nn, 2 * Nn, Nn, Dn,
      2LL * Nn * Nn, (long long)Dn * Nn, (long long)Nn * Dn);

  // 7. h = LN(attout + v)
  add_layernorm<<<dim3(Bn * Nn), blk, 0, stream>>>(ao, QKV, D3, 2 * Dn, gamma, beta, h);

  // 8. out = h @ Wfc + bfc, fp32
  fc_gemm<<<dim3(Dn / BN, M / BM, 1), blk, 0, stream>>>(
      h, WfcT, out, bfc, Dn, Dn, Dn, Dn);
}